// Round 1
// baseline (659.851 us; speedup 1.0000x reference)
//
#include <hip/hip_runtime.h>
#include <math.h>

#define BB 8
#define TT 2048
#define EE 1024
#define DD 128
#define ROWS 16
#define KT 64

// ---------------------------------------------------------------------------
// Kernel 1: QKV projection + RoPE.  C = X(16384x1024) @ W(1024x128); one of
// q/k/v per blockIdx.y. Block = 256 threads -> 128x128 tile, 8x8 micro-tile.
// Micro-tile cols/rows split {4t..4t+3} U {64+4t..} so LDS float4 reads are
// 2-way-conflict max (free on gfx950).
// ---------------------------------------------------------------------------
__global__ __launch_bounds__(256)
void proj_rope_kernel(const float* __restrict__ x,
                      const float* __restrict__ Wq,
                      const float* __restrict__ Wk,
                      const float* __restrict__ Wv,
                      float* __restrict__ qo,
                      float* __restrict__ ko,
                      float* __restrict__ vo)
{
    const int which = blockIdx.y;
    const float* __restrict__ W = (which == 0) ? Wq : (which == 1) ? Wk : Wv;
    float* __restrict__ outp = (which == 0) ? qo : (which == 1) ? ko : vo;

    const int r0  = blockIdx.x * 128;
    const int tid = threadIdx.x;
    const int tx  = tid & 15;   // cols 4tx..4tx+3 and 64+4tx..64+4tx+3
    const int ty  = tid >> 4;   // rows 4ty..4ty+3 and 64+4ty..64+4ty+3

    __shared__ float xs[32][132];   // [k][row]  (transposed x tile, padded)
    __shared__ float wsm[32][132];  // [k][col]

    float acc[8][8];
#pragma unroll
    for (int i = 0; i < 8; i++)
#pragma unroll
        for (int j = 0; j < 8; j++) acc[i][j] = 0.f;

    for (int k0 = 0; k0 < EE; k0 += 32) {
        __syncthreads();
        // stage x tile (128 rows x 32 k), transposed into xs[k][row]
#pragma unroll
        for (int i = 0; i < 4; i++) {
            int e4 = i * 256 + tid;        // 0..1023 float4 ids
            int rr = e4 >> 3;              // 0..127
            int c4 = (e4 & 7) * 4;         // 0,4,..,28
            float4 xv = *(const float4*)&x[(size_t)(r0 + rr) * EE + k0 + c4];
            xs[c4 + 0][rr] = xv.x;
            xs[c4 + 1][rr] = xv.y;
            xs[c4 + 2][rr] = xv.z;
            xs[c4 + 3][rr] = xv.w;
        }
        // stage W tile (32 k x 128 cols)
#pragma unroll
        for (int i = 0; i < 4; i++) {
            int e4 = i * 256 + tid;
            int rr = e4 >> 5;              // 0..31
            int c4 = (e4 & 31) * 4;        // 0..124
            *(float4*)&wsm[rr][c4] = *(const float4*)&W[(size_t)(k0 + rr) * DD + c4];
        }
        __syncthreads();
#pragma unroll
        for (int kk = 0; kk < 32; kk++) {
            float xr[8], wc[8];
            *(float4*)&xr[0] = *(float4*)&xs[kk][4 * ty];
            *(float4*)&xr[4] = *(float4*)&xs[kk][64 + 4 * ty];
            *(float4*)&wc[0] = *(float4*)&wsm[kk][4 * tx];
            *(float4*)&wc[4] = *(float4*)&wsm[kk][64 + 4 * tx];
#pragma unroll
            for (int i = 0; i < 8; i++)
#pragma unroll
                for (int j = 0; j < 8; j++)
                    acc[i][j] = fmaf(xr[i], wc[j], acc[i][j]);
        }
    }

    // ---- epilogue: RoPE (q,k only) + store ----
    // pair indices owned by this thread (independent of row):
    float fr[4];
    if (which < 2) {
        fr[0] = powf(10000.0f, -(float)(2 * tx)      / 64.0f);
        fr[1] = powf(10000.0f, -(float)(2 * tx + 1)  / 64.0f);
        fr[2] = powf(10000.0f, -(float)(32 + 2 * tx)     / 64.0f);
        fr[3] = powf(10000.0f, -(float)(32 + 2 * tx + 1) / 64.0f);
    }
#pragma unroll
    for (int i = 0; i < 8; i++) {
        int row  = (i < 4) ? (4 * ty + i) : (64 + 4 * ty + (i - 4));
        int tpos = (r0 + row) & (TT - 1);   // 128 | 2048 -> blocks never straddle batches
        float o[8];
        if (which < 2) {
#pragma unroll
            for (int h = 0; h < 2; h++) {
#pragma unroll
                for (int pp = 0; pp < 2; pp++) {
                    float ang = (float)tpos * fr[2 * h + pp];
                    float sa, ca;
                    __sincosf(ang, &sa, &ca);
                    float a0 = acc[i][4 * h + 2 * pp];
                    float a1 = acc[i][4 * h + 2 * pp + 1];
                    o[4 * h + 2 * pp]     = a0 * ca - a1 * sa;
                    o[4 * h + 2 * pp + 1] = a0 * sa + a1 * ca;
                }
            }
        } else {
#pragma unroll
            for (int j = 0; j < 8; j++) o[j] = acc[i][j];
        }
        size_t base = (size_t)(r0 + row) * DD;
        *(float4*)&outp[base + 4 * tx]      = make_float4(o[0], o[1], o[2], o[3]);
        *(float4*)&outp[base + 64 + 4 * tx] = make_float4(o[4], o[5], o[6], o[7]);
    }
}

// ---------------------------------------------------------------------------
// Kernel 2: fp32 causal flash attention. Block = 256 (4 waves), 16 q-rows per
// block (4 per wave), K-tile = 64 keys staged in LDS. Online softmax; lane j
// owns key kb0+j for scores, dims (2*lane, 2*lane+1) for the O accumulator.
// ---------------------------------------------------------------------------
__global__ __launch_bounds__(256)
void attn_kernel(const float* __restrict__ q,
                 const float* __restrict__ k,
                 const float* __restrict__ v,
                 float* __restrict__ out)
{
    const int b    = blockIdx.y;
    const int q0   = blockIdx.x * ROWS;
    const int tid  = threadIdx.x;
    const int wave = tid >> 6;
    const int lane = tid & 63;

    __shared__ float4 Ks[KT][33];      // key j, 32 float4 dims (padded)
    __shared__ float  Vs[KT][DD];
    __shared__ float4 Qs[ROWS][32];
    __shared__ float  Ps[4][KT][4];    // [wave][key][row]

    const float* __restrict__ qb = q + (size_t)b * TT * DD;
    const float* __restrict__ kb = k + (size_t)b * TT * DD;
    const float* __restrict__ vb = v + (size_t)b * TT * DD;

#pragma unroll
    for (int i2 = 0; i2 < 2; i2++) {
        int i  = i2 * 256 + tid;       // 0..511 over ROWS*32
        int rr = i >> 5, dd = i & 31;
        Qs[rr][dd] = *(const float4*)&qb[(size_t)(q0 + rr) * DD + dd * 4];
    }

    float m[4], l[4], o0[4], o1[4];
#pragma unroll
    for (int r = 0; r < 4; r++) { m[r] = -1e30f; l[r] = 0.f; o0[r] = 0.f; o1[r] = 0.f; }

    const float scale = 0.088388347648318447f;   // 128^-0.5
    const int kmax = q0 + ROWS - 1;

    for (int kb0 = 0; kb0 <= kmax; kb0 += KT) {
        __syncthreads();   // prev-iter PV readers done before restaging
#pragma unroll
        for (int i2 = 0; i2 < 8; i2++) {
            int i  = i2 * 256 + tid;   // 0..2047 over KT*32
            int jj = i >> 5, dd = i & 31;
            Ks[jj][dd] = *(const float4*)&kb[(size_t)(kb0 + jj) * DD + dd * 4];
        }
#pragma unroll
        for (int i2 = 0; i2 < 8; i2++) {
            int i  = i2 * 256 + tid;
            int jj = i >> 5, dd = i & 31;
            *(float4*)&Vs[jj][dd * 4] = *(const float4*)&vb[(size_t)(kb0 + jj) * DD + dd * 4];
        }
        __syncthreads();

        // scores: lane j = key kb0+j, 4 rows per wave
        float s[4] = {0.f, 0.f, 0.f, 0.f};
#pragma unroll 4
        for (int dd = 0; dd < 32; dd++) {
            float4 kk4 = Ks[lane][dd];
#pragma unroll
            for (int r = 0; r < 4; r++) {
                float4 q4 = Qs[4 * wave + r][dd];
                s[r] = fmaf(q4.x, kk4.x, s[r]);
                s[r] = fmaf(q4.y, kk4.y, s[r]);
                s[r] = fmaf(q4.z, kk4.z, s[r]);
                s[r] = fmaf(q4.w, kk4.w, s[r]);
            }
        }
        int key = kb0 + lane;
        float p4[4];
#pragma unroll
        for (int r = 0; r < 4; r++) {
            int trow = q0 + 4 * wave + r;
            float sv = (key <= trow) ? s[r] * scale : -1e30f;
            float mx = sv;
#pragma unroll
            for (int off = 32; off > 0; off >>= 1)
                mx = fmaxf(mx, __shfl_xor(mx, off));
            float mnew  = fmaxf(m[r], mx);          // > -1e30: every tile has a valid key
            float alpha = __expf(m[r] - mnew);
            float p     = __expf(sv - mnew);
            float ps = p;
#pragma unroll
            for (int off = 32; off > 0; off >>= 1)
                ps += __shfl_xor(ps, off);
            l[r] = l[r] * alpha + ps;
            m[r] = mnew;
            o0[r] *= alpha;
            o1[r] *= alpha;
            p4[r] = p;
        }
        *(float4*)&Ps[wave][lane][0] = make_float4(p4[0], p4[1], p4[2], p4[3]);
        // same-wave LDS RAW: DS ops execute in order within a wave -> no barrier
#pragma unroll 8
        for (int j = 0; j < KT; j++) {
            float2 vv = *(const float2*)&Vs[j][2 * lane];
            float4 pj = *(const float4*)&Ps[wave][j][0];   // broadcast read
            o0[0] = fmaf(pj.x, vv.x, o0[0]); o1[0] = fmaf(pj.x, vv.y, o1[0]);
            o0[1] = fmaf(pj.y, vv.x, o0[1]); o1[1] = fmaf(pj.y, vv.y, o1[1]);
            o0[2] = fmaf(pj.z, vv.x, o0[2]); o1[2] = fmaf(pj.z, vv.y, o1[2]);
            o0[3] = fmaf(pj.w, vv.x, o0[3]); o1[3] = fmaf(pj.w, vv.y, o1[3]);
        }
    }

    float* __restrict__ ob = out + (size_t)b * TT * DD;
#pragma unroll
    for (int r = 0; r < 4; r++) {
        int trow = q0 + 4 * wave + r;
        float inv = 1.0f / l[r];
        *(float2*)&ob[(size_t)trow * DD + 2 * lane] =
            make_float2(o0[r] * inv, o1[r] * inv);
    }
}

extern "C" void kernel_launch(void* const* d_in, const int* in_sizes, int n_in,
                              void* d_out, int out_size, void* d_ws, size_t ws_size,
                              hipStream_t stream)
{
    const float* x  = (const float*)d_in[0];
    const float* Wq = (const float*)d_in[1];
    const float* Wk = (const float*)d_in[2];
    const float* Wv = (const float*)d_in[3];
    float* out = (float*)d_out;

    float* qb = (float*)d_ws;                       // 8 MB
    float* kb = qb + (size_t)BB * TT * DD;          // 8 MB
    float* vb = kb + (size_t)BB * TT * DD;          // 8 MB  (24 MB total)

    dim3 g1(128, 3), b1(256);
    proj_rope_kernel<<<g1, b1, 0, stream>>>(x, Wq, Wk, Wv, qb, kb, vb);

    dim3 g2(TT / ROWS, BB), b2(256);
    attn_kernel<<<g2, b2, 0, stream>>>(qb, kb, vb, out);
}

// Round 2
// 322.389 us; speedup vs baseline: 2.0468x; 2.0468x over previous
//
#include <hip/hip_runtime.h>
#include <math.h>

#define BB 8
#define TT 2048
#define EE 1024
#define DD 128

typedef _Float16 f16x8 __attribute__((ext_vector_type(8)));
typedef _Float16 f16x4 __attribute__((ext_vector_type(4)));
typedef _Float16 f16x2 __attribute__((ext_vector_type(2)));
typedef float    f32x4 __attribute__((ext_vector_type(4)));

// ---------------------------------------------------------------------------
// Kernel 1: QKV projection (fp32 VALU) + RoPE; outputs f16.
// q,k: natural [b*T+t][d].  v: transposed vt[b][d][t] so the attention kernel
// can stage V^T tiles with pure b128 LDS writes.
// ---------------------------------------------------------------------------
__global__ __launch_bounds__(256)
void proj_rope_kernel(const float* __restrict__ x,
                      const float* __restrict__ Wq,
                      const float* __restrict__ Wk,
                      const float* __restrict__ Wv,
                      _Float16* __restrict__ qo,
                      _Float16* __restrict__ ko,
                      _Float16* __restrict__ vt)
{
    const int which = blockIdx.y;
    const float* __restrict__ W = (which == 0) ? Wq : (which == 1) ? Wk : Wv;

    const int r0  = blockIdx.x * 128;
    const int tid = threadIdx.x;
    const int tx  = tid & 15;
    const int ty  = tid >> 4;

    __shared__ float xs[32][132];
    __shared__ float wsm[32][132];

    float acc[8][8];
#pragma unroll
    for (int i = 0; i < 8; i++)
#pragma unroll
        for (int j = 0; j < 8; j++) acc[i][j] = 0.f;

    for (int k0 = 0; k0 < EE; k0 += 32) {
        __syncthreads();
#pragma unroll
        for (int i = 0; i < 4; i++) {
            int e4 = i * 256 + tid;
            int rr = e4 >> 3;
            int c4 = (e4 & 7) * 4;
            float4 xv = *(const float4*)&x[(size_t)(r0 + rr) * EE + k0 + c4];
            xs[c4 + 0][rr] = xv.x;
            xs[c4 + 1][rr] = xv.y;
            xs[c4 + 2][rr] = xv.z;
            xs[c4 + 3][rr] = xv.w;
        }
#pragma unroll
        for (int i = 0; i < 4; i++) {
            int e4 = i * 256 + tid;
            int rr = e4 >> 5;
            int c4 = (e4 & 31) * 4;
            *(float4*)&wsm[rr][c4] = *(const float4*)&W[(size_t)(k0 + rr) * DD + c4];
        }
        __syncthreads();
#pragma unroll
        for (int kk = 0; kk < 32; kk++) {
            float xr[8], wc[8];
            *(float4*)&xr[0] = *(float4*)&xs[kk][4 * ty];
            *(float4*)&xr[4] = *(float4*)&xs[kk][64 + 4 * ty];
            *(float4*)&wc[0] = *(float4*)&wsm[kk][4 * tx];
            *(float4*)&wc[4] = *(float4*)&wsm[kk][64 + 4 * tx];
#pragma unroll
            for (int i = 0; i < 8; i++)
#pragma unroll
                for (int j = 0; j < 8; j++)
                    acc[i][j] = fmaf(xr[i], wc[j], acc[i][j]);
        }
    }

    if (which < 2) {
        // ---- RoPE + natural f16 store ----
        _Float16* __restrict__ outp = (which == 0) ? qo : ko;
        float fr[4];
        fr[0] = powf(10000.0f, -(float)(2 * tx)      / 64.0f);
        fr[1] = powf(10000.0f, -(float)(2 * tx + 1)  / 64.0f);
        fr[2] = powf(10000.0f, -(float)(32 + 2 * tx)     / 64.0f);
        fr[3] = powf(10000.0f, -(float)(32 + 2 * tx + 1) / 64.0f);
#pragma unroll
        for (int i = 0; i < 8; i++) {
            int row  = (i < 4) ? (4 * ty + i) : (64 + 4 * ty + (i - 4));
            int tpos = (r0 + row) & (TT - 1);
            float o[8];
#pragma unroll
            for (int h = 0; h < 2; h++) {
#pragma unroll
                for (int pp = 0; pp < 2; pp++) {
                    float ang = (float)tpos * fr[2 * h + pp];
                    float sa, ca;
                    __sincosf(ang, &sa, &ca);
                    float a0 = acc[i][4 * h + 2 * pp];
                    float a1 = acc[i][4 * h + 2 * pp + 1];
                    o[4 * h + 2 * pp]     = a0 * ca - a1 * sa;
                    o[4 * h + 2 * pp + 1] = a0 * sa + a1 * ca;
                }
            }
            size_t base = (size_t)(r0 + row) * DD;
            f16x4 h0 = { (_Float16)o[0], (_Float16)o[1], (_Float16)o[2], (_Float16)o[3] };
            f16x4 h1 = { (_Float16)o[4], (_Float16)o[5], (_Float16)o[6], (_Float16)o[7] };
            *(f16x4*)&outp[base + 4 * tx]      = h0;
            *(f16x4*)&outp[base + 64 + 4 * tx] = h1;
        }
    } else {
        // ---- V: transposed store vt[b][d][t], f16x2 along t ----
        int bidx = r0 >> 11;                // block never straddles batches
        int tb0  = (r0 + 4 * ty) & (TT - 1);
        int tb1  = (r0 + 64 + 4 * ty) & (TT - 1);
#pragma unroll
        for (int j = 0; j < 8; j++) {
            int d = (j < 4) ? (4 * tx + j) : (64 + 4 * tx + (j - 4));
            _Float16* vp = vt + ((size_t)bidx * DD + d) * TT;
            f16x2 p01 = { (_Float16)acc[0][j], (_Float16)acc[1][j] };
            f16x2 p23 = { (_Float16)acc[2][j], (_Float16)acc[3][j] };
            f16x2 p45 = { (_Float16)acc[4][j], (_Float16)acc[5][j] };
            f16x2 p67 = { (_Float16)acc[6][j], (_Float16)acc[7][j] };
            *(f16x2*)&vp[tb0]     = p01;
            *(f16x2*)&vp[tb0 + 2] = p23;
            *(f16x2*)&vp[tb1]     = p45;
            *(f16x2*)&vp[tb1 + 2] = p67;
        }
    }
}

// ---------------------------------------------------------------------------
// Kernel 2: MFMA flash attention. Block = 128 (2 waves), Q-tile 32 (16 rows
// per wave), K-tile 64. mfma_f32_16x16x32_f16.
// Layouts (guide §3, m89/m120 verified):
//   A[m=lane&15][k=quad*8+j], B[k=quad*8+j][n=lane&15],
//   C/D[row=quad*4+reg][col=lane&15].
// P goes through LDS (C-layout -> A-layout round-trip, same wave only).
// ---------------------------------------------------------------------------
__global__ __launch_bounds__(128)
void attn_kernel(const _Float16* __restrict__ qh,
                 const _Float16* __restrict__ kh,
                 const _Float16* __restrict__ vth,
                 float* __restrict__ out)
{
    const int b    = blockIdx.y;
    // pair long+short tiles across co-resident blocks (perf heuristic only)
    const int xt   = (blockIdx.y & 4) ? (gridDim.x - 1 - blockIdx.x) : blockIdx.x;
    const int q0   = xt * 32;
    const int tid  = threadIdx.x;
    const int wave = tid >> 6;
    const int lane = tid & 63;
    const int quad = lane >> 4;
    const int col  = lane & 15;

    __shared__ _Float16 Ks[64][136];    // [key][dim], +8 pad -> bank-balanced b128
    __shared__ _Float16 Vt[128][72];    // [dim][key], +8 pad
    __shared__ _Float16 Ps[2][16][72];  // [wave][row][key], +8 pad

    // Q A-fragments, straight from global (16B contiguous per lane)
    const int qrow = q0 + wave * 16 + col;
    f16x8 qa[4];
#pragma unroll
    for (int kc = 0; kc < 4; kc++)
        qa[kc] = *(const f16x8*)&qh[((size_t)b * TT + qrow) * DD + kc * 32 + quad * 8];

    f32x4 Of[8];
#pragma unroll
    for (int n = 0; n < 8; n++) Of[n] = (f32x4)0.f;
    float m[4], l[4];
#pragma unroll
    for (int r = 0; r < 4; r++) { m[r] = -1e30f; l[r] = 0.f; }

    const float scale = 0.088388347648318447f;  // 128^-0.5

    for (int kb0 = 0; kb0 <= q0 + 31; kb0 += 64) {
        __syncthreads();
        // stage K tile: 64 keys x 128 dims
#pragma unroll
        for (int i = 0; i < 8; i++) {
            int idx = i * 128 + tid;
            int key = idx >> 4, c = idx & 15;
            f16x8 t8 = *(const f16x8*)&kh[((size_t)b * TT + kb0 + key) * DD + c * 8];
            *(f16x8*)&Ks[key][c * 8] = t8;
        }
        // stage V^T tile: 128 dims x 64 keys (already transposed in global)
#pragma unroll
        for (int i = 0; i < 8; i++) {
            int idx = i * 128 + tid;
            int d = idx >> 3, c = idx & 7;
            f16x8 t8 = *(const f16x8*)&vth[((size_t)b * DD + d) * TT + kb0 + c * 8];
            *(f16x8*)&Vt[d][c * 8] = t8;
        }
        __syncthreads();

        // ---- S = Q K^T ----
        f32x4 sf[4];
#pragma unroll
        for (int g = 0; g < 4; g++) {
            sf[g] = (f32x4)0.f;
#pragma unroll
            for (int kc = 0; kc < 4; kc++) {
                f16x8 kf = *(f16x8*)&Ks[g * 16 + col][kc * 32 + quad * 8];
                sf[g] = __builtin_amdgcn_mfma_f32_16x16x32_f16(qa[kc], kf, sf[g], 0, 0, 0);
            }
        }

        // ---- online softmax (C-layout: row = quad*4+r, col = key) ----
#pragma unroll
        for (int r = 0; r < 4; r++) {
            int row = q0 + wave * 16 + quad * 4 + r;   // absolute query pos
            float sv[4];
#pragma unroll
            for (int g = 0; g < 4; g++) {
                int key = kb0 + g * 16 + col;
                sv[g] = (key <= row) ? sf[g][r] * scale : -1e30f;
            }
            float mloc = fmaxf(fmaxf(sv[0], sv[1]), fmaxf(sv[2], sv[3]));
#pragma unroll
            for (int off = 1; off < 16; off <<= 1)
                mloc = fmaxf(mloc, __shfl_xor(mloc, off));
            float mnew  = fmaxf(m[r], mloc);
            float alpha = __expf(m[r] - mnew);
            float p[4], ps = 0.f;
#pragma unroll
            for (int g = 0; g < 4; g++) { p[g] = __expf(sv[g] - mnew); ps += p[g]; }
#pragma unroll
            for (int off = 1; off < 16; off <<= 1)
                ps += __shfl_xor(ps, off);
            l[r] = l[r] * alpha + ps;
            m[r] = mnew;
#pragma unroll
            for (int n = 0; n < 8; n++) Of[n][r] *= alpha;
#pragma unroll
            for (int g = 0; g < 4; g++)
                Ps[wave][quad * 4 + r][g * 16 + col] = (_Float16)p[g];
        }

        // ---- O += P V  (P via LDS round-trip; same-wave RAW, no barrier) ----
        f16x8 pa[2];
#pragma unroll
        for (int kc = 0; kc < 2; kc++)
            pa[kc] = *(f16x8*)&Ps[wave][col][kc * 32 + quad * 8];
#pragma unroll
        for (int n = 0; n < 8; n++) {
#pragma unroll
            for (int kc = 0; kc < 2; kc++) {
                f16x8 vf = *(f16x8*)&Vt[n * 16 + col][kc * 32 + quad * 8];
                Of[n] = __builtin_amdgcn_mfma_f32_16x16x32_f16(pa[kc], vf, Of[n], 0, 0, 0);
            }
        }
    }

    // ---- epilogue ----
#pragma unroll
    for (int r = 0; r < 4; r++) {
        int row = q0 + wave * 16 + quad * 4 + r;
        float inv = 1.0f / l[r];
        float* op = out + ((size_t)b * TT + row) * DD;
#pragma unroll
        for (int n = 0; n < 8; n++)
            op[n * 16 + col] = Of[n][r] * inv;
    }
}

extern "C" void kernel_launch(void* const* d_in, const int* in_sizes, int n_in,
                              void* d_out, int out_size, void* d_ws, size_t ws_size,
                              hipStream_t stream)
{
    const float* x  = (const float*)d_in[0];
    const float* Wq = (const float*)d_in[1];
    const float* Wk = (const float*)d_in[2];
    const float* Wv = (const float*)d_in[3];
    float* out = (float*)d_out;

    _Float16* qh = (_Float16*)d_ws;                     // 4 MB
    _Float16* kh = qh + (size_t)BB * TT * DD;           // 4 MB
    _Float16* vt = kh + (size_t)BB * TT * DD;           // 4 MB

    dim3 g1(128, 3), b1(256);
    proj_rope_kernel<<<g1, b1, 0, stream>>>(x, Wq, Wk, Wv, qh, kh, vt);

    dim3 g2(64, BB), b2(128);
    attn_kernel<<<g2, b2, 0, stream>>>(qh, kh, vt, out);
}

// Round 3
// 272.711 us; speedup vs baseline: 2.4196x; 1.1822x over previous
//
#include <hip/hip_runtime.h>
#include <math.h>

#define BB 8
#define TT 2048
#define EE 1024
#define DD 128

typedef _Float16 f16x8 __attribute__((ext_vector_type(8)));
typedef _Float16 f16x4 __attribute__((ext_vector_type(4)));
typedef float    f32x4 __attribute__((ext_vector_type(4)));

// scale (128^-0.5) * log2(e): folded into q so softmax uses exp2 directly
#define QSCALE 0.12752406f

// ---------------------------------------------------------------------------
// Kernel 0: W transpose+cast.  Wt[384][1024] f16; rows 0-127=Wq cols,
// 128-255=Wk, 256-383=Wv.  W is tiny (1.5 MB) -> L2 absorbs the strided reads.
// ---------------------------------------------------------------------------
__global__ __launch_bounds__(256)
void wt_prep_kernel(const float* __restrict__ Wq,
                    const float* __restrict__ Wk,
                    const float* __restrict__ Wv,
                    _Float16* __restrict__ Wt)
{
    const int n = blockIdx.x;               // 0..383
    const int m = n >> 7;
    const float* __restrict__ W = (m == 0) ? Wq : (m == 1) ? Wk : Wv;
    const int nl = n & 127;
#pragma unroll
    for (int j = 0; j < 4; j++) {
        int kk = threadIdx.x + 256 * j;
        Wt[(size_t)n * EE + kk] = (_Float16)W[(size_t)kk * DD + nl];
    }
}

// ---------------------------------------------------------------------------
// Kernel 1: fused QKV projection via MFMA + RoPE epilogue.
// Block: 512 thr = 8 waves (wave_m in {0,1} x wave_n in {0..3}).
// Tile: M=64 rows x N=384 (q|k|v), BK=32.  grid = 256 blocks (1/CU).
// Frag layouts (guide §3): A[m=lane&15][k=quad*8+j], B[k][n=lane&15],
// C[row=quad*4+r][col=lane&15].
// ---------------------------------------------------------------------------
__global__ __launch_bounds__(512)
void proj_rope_kernel(const float* __restrict__ x,
                      const _Float16* __restrict__ Wt,
                      _Float16* __restrict__ qh,
                      _Float16* __restrict__ kh,
                      _Float16* __restrict__ vt)
{
    const int r0   = blockIdx.x * 64;       // global row (b*T+t), 64|2048
    const int tid  = threadIdx.x;
    const int wave = tid >> 6;
    const int lane = tid & 63;
    const int quad = lane >> 4;
    const int col  = lane & 15;
    const int wave_m = wave & 1;            // 2 m-subtiles of 16
    const int wave_n = wave >> 1;           // 6 n-subtiles of 16

    __shared__ _Float16 Xs[64][40];         // [row][k], stride 80B (16B-mult)
    __shared__ _Float16 Ws[384][40];        // [n][k]
    __shared__ _Float16 Out[64][136];       // epilogue coalescing buffer

    f32x4 acc[2][6];
#pragma unroll
    for (int mi = 0; mi < 2; mi++)
#pragma unroll
        for (int ni = 0; ni < 6; ni++) acc[mi][ni] = (f32x4)0.f;

    for (int k0 = 0; k0 < EE; k0 += 32) {
        __syncthreads();
        // stage X (64x32 f32 -> f16): one float4 per thread
        {
            int row = tid >> 3, c4 = (tid & 7) * 4;
            float4 xv = *(const float4*)&x[(size_t)(r0 + row) * EE + k0 + c4];
            f16x4 h = { (_Float16)xv.x, (_Float16)xv.y, (_Float16)xv.z, (_Float16)xv.w };
            *(f16x4*)&Xs[row][c4] = h;
        }
        // stage Wt slice (384 x 32 f16): 3 x f16x8 per thread
#pragma unroll
        for (int j = 0; j < 3; j++) {
            int ch = tid + 512 * j;         // 0..1535
            int nn = ch >> 2, c8 = (ch & 3) * 8;
            *(f16x8*)&Ws[nn][c8] = *(const f16x8*)&Wt[(size_t)nn * EE + k0 + c8];
        }
        __syncthreads();

        f16x8 a[2], bfr[6];
#pragma unroll
        for (int mi = 0; mi < 2; mi++)
            a[mi] = *(f16x8*)&Xs[wave_m * 32 + mi * 16 + col][quad * 8];
#pragma unroll
        for (int ni = 0; ni < 6; ni++)
            bfr[ni] = *(f16x8*)&Ws[wave_n * 96 + ni * 16 + col][quad * 8];
#pragma unroll
        for (int mi = 0; mi < 2; mi++)
#pragma unroll
            for (int ni = 0; ni < 6; ni++)
                acc[mi][ni] = __builtin_amdgcn_mfma_f32_16x16x32_f16(a[mi], bfr[ni], acc[mi][ni], 0, 0, 0);
    }

    // ---- epilogue: 3 passes (q,k,v) through Out for coalesced stores ----
    const int bidx = r0 >> 11;
    const int t0   = r0 & (TT - 1);

    for (int p = 0; p < 3; p++) {
        __syncthreads();
#pragma unroll
        for (int ni = 0; ni < 6; ni++) {
            int gn = wave_n * 6 + ni;       // global n-subtile 0..23
            if ((gn >> 3) != p) continue;
            int dcol = (gn & 7) * 16 + col; // 0..127 within matrix p
            float f = 0.f;
            if (p < 2)
                f = __powf(10000.0f, -(float)(dcol & ~1) * (1.0f / 128.0f));
#pragma unroll
            for (int mi = 0; mi < 2; mi++) {
#pragma unroll
                for (int r = 0; r < 4; r++) {
                    int mrow = wave_m * 32 + mi * 16 + quad * 4 + r;
                    float av = acc[mi][ni][r];
                    float res;
                    if (p < 2) {
                        float ap = __shfl_xor(av, 1);   // RoPE pair partner
                        float sa, ca;
                        __sincosf((float)(t0 + mrow) * f, &sa, &ca);
                        res = av * ca + ap * ((dcol & 1) ? sa : -sa);
                        if (p == 0) res *= QSCALE;
                    } else {
                        res = av;
                    }
                    Out[mrow][dcol] = (_Float16)res;
                }
            }
        }
        __syncthreads();
        if (p < 2) {
            _Float16* __restrict__ dst = ((p == 0) ? qh : kh) + (size_t)r0 * DD;
#pragma unroll
            for (int j = 0; j < 2; j++) {
                int c = tid + 512 * j;      // 0..1023 16B-chunks
                int row = c >> 4, o = c & 15;
                *(f16x8*)&dst[(size_t)row * DD + o * 8] = *(f16x8*)&Out[row][o * 8];
            }
        } else {
#pragma unroll
            for (int j = 0; j < 4; j++) {
                int u = tid + 512 * j;      // 0..2047: 128 d x 16 t-groups
                int d = u >> 4, tg = u & 15;
                f16x4 vv = { Out[tg * 4 + 0][d], Out[tg * 4 + 1][d],
                             Out[tg * 4 + 2][d], Out[tg * 4 + 3][d] };
                *(f16x4*)&vt[((size_t)(bidx * DD + d)) * TT + t0 + tg * 4] = vv;
            }
        }
    }
}

// ---------------------------------------------------------------------------
// Kernel 2: MFMA flash attention, split-K x2 with unnormalized partials.
// Block = 128 thr (2 waves), Q-tile 32.  grid.x = 128: u -> (v=u>>1, s=u&1),
// xt = mirror(v) so consecutive block pairs carry uniform total work.
// q pre-scaled by scale*log2e -> softmax in exp2 domain.
// ---------------------------------------------------------------------------
__global__ __launch_bounds__(128)
void attn_kernel(const _Float16* __restrict__ qh,
                 const _Float16* __restrict__ kh,
                 const _Float16* __restrict__ vth,
                 float* __restrict__ opart,
                 float* __restrict__ mpart,
                 float* __restrict__ lpart)
{
    const int b  = blockIdx.y;
    const int u  = blockIdx.x;
    const int s  = u & 1;
    const int v  = u >> 1;
    const int xt = (v & 1) ? (63 - (v >> 1)) : (v >> 1);
    const int q0 = xt * 32;
    const int n  = (xt >> 1) + 1;           // causal k-tiles for this q-tile
    const int n0 = (n + 1) >> 1;
    const int kt_begin = s ? n0 : 0;
    const int kt_end   = s ? n : n0;

    const int tid  = threadIdx.x;
    const int wave = tid >> 6;
    const int lane = tid & 63;
    const int quad = lane >> 4;
    const int col  = lane & 15;

    __shared__ _Float16 Ks[64][136];
    __shared__ _Float16 Vt[128][72];
    __shared__ _Float16 Ps[2][16][72];

    const int qrow = q0 + wave * 16 + col;
    f16x8 qa[4];
#pragma unroll
    for (int kc = 0; kc < 4; kc++)
        qa[kc] = *(const f16x8*)&qh[((size_t)b * TT + qrow) * DD + kc * 32 + quad * 8];

    f32x4 Of[8];
#pragma unroll
    for (int nn = 0; nn < 8; nn++) Of[nn] = (f32x4)0.f;
    float m[4], l[4];
#pragma unroll
    for (int r = 0; r < 4; r++) { m[r] = -1e30f; l[r] = 0.f; }

    for (int kt = kt_begin; kt < kt_end; kt++) {
        const int kb0 = kt * 64;
        __syncthreads();
#pragma unroll
        for (int i = 0; i < 8; i++) {
            int idx = i * 128 + tid;
            int key = idx >> 4, c = idx & 15;
            *(f16x8*)&Ks[key][c * 8] =
                *(const f16x8*)&kh[((size_t)b * TT + kb0 + key) * DD + c * 8];
        }
#pragma unroll
        for (int i = 0; i < 8; i++) {
            int idx = i * 128 + tid;
            int d = idx >> 3, c = idx & 7;
            *(f16x8*)&Vt[d][c * 8] =
                *(const f16x8*)&vth[((size_t)b * DD + d) * TT + kb0 + c * 8];
        }
        __syncthreads();

        f32x4 sf[4];
#pragma unroll
        for (int g = 0; g < 4; g++) {
            sf[g] = (f32x4)0.f;
#pragma unroll
            for (int kc = 0; kc < 4; kc++) {
                f16x8 kf = *(f16x8*)&Ks[g * 16 + col][kc * 32 + quad * 8];
                sf[g] = __builtin_amdgcn_mfma_f32_16x16x32_f16(qa[kc], kf, sf[g], 0, 0, 0);
            }
        }

#pragma unroll
        for (int r = 0; r < 4; r++) {
            int row = q0 + wave * 16 + quad * 4 + r;
            float sv[4];
#pragma unroll
            for (int g = 0; g < 4; g++) {
                int key = kb0 + g * 16 + col;
                sv[g] = (key <= row) ? sf[g][r] : -1e30f;   // exp2 (log2) domain
            }
            float mloc = fmaxf(fmaxf(sv[0], sv[1]), fmaxf(sv[2], sv[3]));
#pragma unroll
            for (int off = 1; off < 16; off <<= 1)
                mloc = fmaxf(mloc, __shfl_xor(mloc, off));
            float mnew  = fmaxf(m[r], mloc);
            float alpha = __builtin_amdgcn_exp2f(m[r] - mnew);
            float p[4], ps = 0.f;
#pragma unroll
            for (int g = 0; g < 4; g++) {
                p[g] = __builtin_amdgcn_exp2f(sv[g] - mnew);
                ps += p[g];
            }
#pragma unroll
            for (int off = 1; off < 16; off <<= 1)
                ps += __shfl_xor(ps, off);
            l[r] = l[r] * alpha + ps;
            m[r] = mnew;
#pragma unroll
            for (int nn = 0; nn < 8; nn++) Of[nn][r] *= alpha;
#pragma unroll
            for (int g = 0; g < 4; g++)
                Ps[wave][quad * 4 + r][g * 16 + col] = (_Float16)p[g];
        }

        f16x8 pa[2];
#pragma unroll
        for (int kc = 0; kc < 2; kc++)
            pa[kc] = *(f16x8*)&Ps[wave][col][kc * 32 + quad * 8];
#pragma unroll
        for (int nn = 0; nn < 8; nn++) {
#pragma unroll
            for (int kc = 0; kc < 2; kc++) {
                f16x8 vf = *(f16x8*)&Vt[nn * 16 + col][kc * 32 + quad * 8];
                Of[nn] = __builtin_amdgcn_mfma_f32_16x16x32_f16(pa[kc], vf, Of[nn], 0, 0, 0);
            }
        }
    }

    // ---- partial epilogue (unnormalized) ----
#pragma unroll
    for (int r = 0; r < 4; r++) {
        int rowl = q0 + wave * 16 + quad * 4 + r;
        size_t gr = (size_t)s * (BB * TT) + (size_t)b * TT + rowl;
        float* op = opart + gr * DD;
#pragma unroll
        for (int nn = 0; nn < 8; nn++)
            op[nn * 16 + col] = Of[nn][r];
        if (col == 0) {
            mpart[gr] = m[r];
            lpart[gr] = l[r];
        }
    }
}

// ---------------------------------------------------------------------------
// Kernel 3: combine the two split-K partials.
// ---------------------------------------------------------------------------
__global__ __launch_bounds__(256)
void combine_kernel(const float* __restrict__ opart,
                    const float* __restrict__ mpart,
                    const float* __restrict__ lpart,
                    float* __restrict__ out)
{
    int gid = blockIdx.x * 256 + threadIdx.x;     // 0..2M-1
    int row = gid >> 7;                           // 0..16383
    float m0 = mpart[row], m1 = mpart[BB * TT + row];
    float l0 = lpart[row], l1 = lpart[BB * TT + row];
    float mm = fmaxf(m0, m1);
    float w0 = __builtin_amdgcn_exp2f(m0 - mm);
    float w1 = __builtin_amdgcn_exp2f(m1 - mm);
    float inv = 1.0f / (w0 * l0 + w1 * l1);
    float o0 = opart[gid];
    float o1 = opart[(size_t)(BB * TT) * DD + gid];
    out[gid] = (w0 * o0 + w1 * o1) * inv;
}

extern "C" void kernel_launch(void* const* d_in, const int* in_sizes, int n_in,
                              void* d_out, int out_size, void* d_ws, size_t ws_size,
                              hipStream_t stream)
{
    const float* x  = (const float*)d_in[0];
    const float* Wq = (const float*)d_in[1];
    const float* Wk = (const float*)d_in[2];
    const float* Wv = (const float*)d_in[3];
    float* out = (float*)d_out;

    const size_t NTOK = (size_t)BB * TT;          // 16384
    _Float16* qh = (_Float16*)d_ws;               // 4 MB
    _Float16* kh = qh + NTOK * DD;                // 4 MB
    _Float16* vt = kh + NTOK * DD;                // 4 MB
    _Float16* Wt = vt + NTOK * DD;                // 0.75 MB
    float* opart = (float*)((char*)d_ws + (3 * NTOK * DD + 384 * EE) * sizeof(_Float16));
    float* mp    = opart + 2 * NTOK * DD;         // 16 MB opart
    float* lp    = mp + 2 * NTOK;

    wt_prep_kernel<<<dim3(384), dim3(256), 0, stream>>>(Wq, Wk, Wv, Wt);
    proj_rope_kernel<<<dim3(256), dim3(512), 0, stream>>>(x, Wt, qh, kh, vt);
    attn_kernel<<<dim3(128, BB), dim3(128), 0, stream>>>(qh, kh, vt, opart, mp, lp);
    combine_kernel<<<dim3((int)(NTOK * DD / 256)), dim3(256), 0, stream>>>(opart, mp, lp, out);
}

// Round 4
// 196.117 us; speedup vs baseline: 3.3646x; 1.3906x over previous
//
#include <hip/hip_runtime.h>
#include <math.h>

#define BB 8
#define TT 2048
#define EE 1024
#define DD 128

typedef _Float16 f16x8 __attribute__((ext_vector_type(8)));
typedef _Float16 f16x4 __attribute__((ext_vector_type(4)));
typedef float    f32x4 __attribute__((ext_vector_type(4)));

// scale (128^-0.5) * log2(e): folded into q so softmax runs in exp2 domain
#define QSCALE 0.12752406f

// ---------------------------------------------------------------------------
// Kernel 0: W transpose+cast.  Wt[384][1024] f16 (rows 0-127=Wq^T, etc).
// ---------------------------------------------------------------------------
__global__ __launch_bounds__(256)
void wt_prep_kernel(const float* __restrict__ Wq,
                    const float* __restrict__ Wk,
                    const float* __restrict__ Wv,
                    _Float16* __restrict__ Wt)
{
    const int n = blockIdx.x;               // 0..383
    const int m = n >> 7;
    const float* __restrict__ W = (m == 0) ? Wq : (m == 1) ? Wk : Wv;
    const int nl = n & 127;
#pragma unroll
    for (int j = 0; j < 4; j++) {
        int kk = threadIdx.x + 256 * j;
        Wt[(size_t)n * EE + kk] = (_Float16)W[(size_t)kk * DD + nl];
    }
}

// ---------------------------------------------------------------------------
// Kernel 1: fused QKV projection via MFMA + RoPE epilogue.
// M-tile 32, N = 384 (q|k|v fused so X is read once), BK=32.
// 512 thr = 8 waves: wave_m in {0,1} x wave_n in {0..3} (6 n-subtiles each).
// grid = 512 blocks -> 2-3 blocks/CU for cross-block latency hiding.
// ---------------------------------------------------------------------------
__global__ __launch_bounds__(512)
void proj_rope_kernel(const float* __restrict__ x,
                      const _Float16* __restrict__ Wt,
                      _Float16* __restrict__ qh,
                      _Float16* __restrict__ kh,
                      _Float16* __restrict__ vt)
{
    const int r0   = blockIdx.x * 32;       // global row (b*T+t), 32|2048
    const int tid  = threadIdx.x;
    const int wave = tid >> 6;
    const int lane = tid & 63;
    const int quad = lane >> 4;
    const int col  = lane & 15;
    const int wave_m = wave & 1;
    const int wave_n = wave >> 1;

    __shared__ _Float16 Xs[32][40];
    __shared__ _Float16 Ws[384][40];
    __shared__ _Float16 Out[32][136];

    f32x4 acc[6];
#pragma unroll
    for (int ni = 0; ni < 6; ni++) acc[ni] = (f32x4)0.f;

    for (int k0 = 0; k0 < EE; k0 += 32) {
        __syncthreads();
        if (tid < 256) {                    // X tile 32x32 f32 -> f16
            int row = tid >> 3, c4 = (tid & 7) * 4;
            float4 xv = *(const float4*)&x[(size_t)(r0 + row) * EE + k0 + c4];
            f16x4 h = { (_Float16)xv.x, (_Float16)xv.y, (_Float16)xv.z, (_Float16)xv.w };
            *(f16x4*)&Xs[row][c4] = h;
        }
#pragma unroll
        for (int j = 0; j < 3; j++) {       // Wt slice 384x32
            int ch = tid + 512 * j;         // 0..1535
            int nn = ch >> 2, c8 = (ch & 3) * 8;
            *(f16x8*)&Ws[nn][c8] = *(const f16x8*)&Wt[(size_t)nn * EE + k0 + c8];
        }
        __syncthreads();

        f16x8 a = *(f16x8*)&Xs[wave_m * 16 + col][quad * 8];
#pragma unroll
        for (int ni = 0; ni < 6; ni++) {
            f16x8 bfr = *(f16x8*)&Ws[wave_n * 96 + ni * 16 + col][quad * 8];
            acc[ni] = __builtin_amdgcn_mfma_f32_16x16x32_f16(a, bfr, acc[ni], 0, 0, 0);
        }
    }

    // ---- epilogue: 3 passes (q,k,v) through Out for coalesced stores ----
    const int bidx = r0 >> 11;
    const int t0   = r0 & (TT - 1);

    for (int p = 0; p < 3; p++) {
        __syncthreads();
#pragma unroll
        for (int ni = 0; ni < 6; ni++) {
            int gn = wave_n * 6 + ni;       // 0..23
            if ((gn >> 3) != p) continue;
            int dcol = (gn & 7) * 16 + col;
            float f = 0.f;
            if (p < 2)
                f = __powf(10000.0f, -(float)(dcol & ~1) * (1.0f / 128.0f));
#pragma unroll
            for (int r = 0; r < 4; r++) {
                int mrow = wave_m * 16 + quad * 4 + r;
                float av = acc[ni][r];
                float res;
                if (p < 2) {
                    float ap = __shfl_xor(av, 1);
                    float sa, ca;
                    __sincosf((float)(t0 + mrow) * f, &sa, &ca);
                    res = av * ca + ap * ((dcol & 1) ? sa : -sa);
                    if (p == 0) res *= QSCALE;
                } else {
                    res = av;
                }
                Out[mrow][dcol] = (_Float16)res;
            }
        }
        __syncthreads();
        if (p < 2) {
            _Float16* __restrict__ dst = ((p == 0) ? qh : kh) + (size_t)r0 * DD;
            int row = tid >> 4, o = tid & 15;   // 512 = 32 rows x 16 chunks
            *(f16x8*)&dst[(size_t)row * DD + o * 8] = *(f16x8*)&Out[row][o * 8];
        } else {
#pragma unroll
            for (int j = 0; j < 2; j++) {
                int u = tid + 512 * j;      // 0..1023: 128 d x 8 t-groups
                int d = u >> 3, tg = u & 7;
                f16x4 vv = { Out[tg * 4 + 0][d], Out[tg * 4 + 1][d],
                             Out[tg * 4 + 2][d], Out[tg * 4 + 3][d] };
                *(f16x4*)&vt[((size_t)(bidx * DD + d)) * TT + t0 + tg * 4] = vv;
            }
        }
    }
}

// ---------------------------------------------------------------------------
// Kernel 2: MFMA flash attention, TRANSPOSED softmax (S^T = K Q^T).
// C-layout rows = keys, cols = queries -> each lane owns ONE query; the
// softmax reduction is 15 VALU + 2 shfl (xor 16,32) instead of 4x(4+4) shfl.
// Block 256 thr (4 waves x 16 q), Q-tile 64, K-tile 64, chunked split-K
// (8 k-tiles per chunk) with f16 unnormalized partials.
// ---------------------------------------------------------------------------
__global__ __launch_bounds__(256)
void attn_kernel(const _Float16* __restrict__ qh,
                 const _Float16* __restrict__ kh,
                 const _Float16* __restrict__ vth,
                 _Float16* __restrict__ opart,
                 float* __restrict__ mpart,
                 float* __restrict__ lpart)
{
    const int b = blockIdx.y;
    const int u = blockIdx.x;               // 0..79
    int xt, c;
    if (u < 8)       { xt = u;                 c = 0; }
    else if (u < 24) { xt = 8 + ((u - 8) >> 1);  c = (u - 8) & 1; }
    else if (u < 48) { xt = 16 + (u - 24) / 3;   c = (u - 24) % 3; }
    else             { xt = 24 + ((u - 48) >> 2); c = (u - 48) & 3; }
    const int q0 = xt * 64;
    const int n  = xt + 1;                  // causal 64-key tiles for this q-tile
    const int kt_begin = c * 8;
    const int kt_end   = (kt_begin + 8 < n) ? (kt_begin + 8) : n;

    const int tid  = threadIdx.x;
    const int wave = tid >> 6;
    const int lane = tid & 63;
    const int quad = lane >> 4;
    const int col  = lane & 15;

    __shared__ _Float16 Ks[64][136];        // [key][dim]
    __shared__ _Float16 Vt[128][72];        // [dim][key]
    __shared__ _Float16 Ps[4][16][72];      // [wave][q][key]

    const int qg = q0 + wave * 16 + col;    // this lane's query row
    f16x8 qb[4];                            // Q as B-frag: B[k=d][n=q]
#pragma unroll
    for (int kc = 0; kc < 4; kc++)
        qb[kc] = *(const f16x8*)&qh[((size_t)b * TT + qg) * DD + kc * 32 + quad * 8];

    f32x4 Of[8];                            // O^T tiles [d-subtile][q]
#pragma unroll
    for (int nn = 0; nn < 8; nn++) Of[nn] = (f32x4)0.f;
    float m_ = -1e30f, l_ = 0.f;

    for (int kt = kt_begin; kt < kt_end; kt++) {
        const int kb0 = kt * 64;
        __syncthreads();
#pragma unroll
        for (int i = 0; i < 4; i++) {
            int idx = i * 256 + tid;        // 1024 chunks: 64 keys x 16
            int key = idx >> 4, cc = idx & 15;
            *(f16x8*)&Ks[key][cc * 8] =
                *(const f16x8*)&kh[((size_t)b * TT + kb0 + key) * DD + cc * 8];
        }
#pragma unroll
        for (int i = 0; i < 4; i++) {
            int idx = i * 256 + tid;        // 1024 chunks: 128 dims x 8
            int d = idx >> 3, cc = idx & 7;
            *(f16x8*)&Vt[d][cc * 8] =
                *(const f16x8*)&vth[((size_t)b * DD + d) * TT + kb0 + cc * 8];
        }
        __syncthreads();

        // ---- S^T = K Q^T : A=K-frag, B=Q-frag; C rows=keys, cols=queries ----
        f32x4 sf[4];
#pragma unroll
        for (int g = 0; g < 4; g++) {
            sf[g] = (f32x4)0.f;
#pragma unroll
            for (int kc = 0; kc < 4; kc++) {
                f16x8 kf = *(f16x8*)&Ks[g * 16 + col][kc * 32 + quad * 8];
                sf[g] = __builtin_amdgcn_mfma_f32_16x16x32_f16(kf, qb[kc], sf[g], 0, 0, 0);
            }
        }

        // ---- per-lane softmax over 16 local keys + 2-shfl quad reduction ----
        float sv[4][4];
        float mloc = -1e30f;
        const bool diag = (kt == xt);       // only the diagonal tile needs masking
#pragma unroll
        for (int g = 0; g < 4; g++)
#pragma unroll
            for (int r = 0; r < 4; r++) {
                int key = kb0 + g * 16 + quad * 4 + r;
                float v = sf[g][r];
                sv[g][r] = (!diag || key <= qg) ? v : -1e30f;
                mloc = fmaxf(mloc, sv[g][r]);
            }
        mloc = fmaxf(mloc, __shfl_xor(mloc, 16));
        mloc = fmaxf(mloc, __shfl_xor(mloc, 32));
        float mnew  = fmaxf(m_, mloc);
        float alpha = __builtin_amdgcn_exp2f(m_ - mnew);
        float ps = 0.f;
#pragma unroll
        for (int g = 0; g < 4; g++) {
            f16x4 p4;
#pragma unroll
            for (int r = 0; r < 4; r++) {
                float p = __builtin_amdgcn_exp2f(sv[g][r] - mnew);
                ps += p;
                p4[r] = (_Float16)p;
            }
            *(f16x4*)&Ps[wave][col][g * 16 + quad * 4] = p4;
        }
        ps += __shfl_xor(ps, 16);
        ps += __shfl_xor(ps, 32);
        l_ = l_ * alpha + ps;
        m_ = mnew;
#pragma unroll
        for (int nn = 0; nn < 8; nn++) Of[nn] *= alpha;

        // ---- O^T += V^T P^T (P via same-wave LDS round-trip, in-order DS) ----
        f16x8 pb[2];
#pragma unroll
        for (int kc = 0; kc < 2; kc++)
            pb[kc] = *(f16x8*)&Ps[wave][col][kc * 32 + quad * 8];
#pragma unroll
        for (int nn = 0; nn < 8; nn++) {
#pragma unroll
            for (int kc = 0; kc < 2; kc++) {
                f16x8 vf = *(f16x8*)&Vt[nn * 16 + col][kc * 32 + quad * 8];
                Of[nn] = __builtin_amdgcn_mfma_f32_16x16x32_f16(vf, pb[kc], Of[nn], 0, 0, 0);
            }
        }
    }

    // ---- partial store (f16 unnormalized O, f32 m/l) ----
    const int slot = (b * 32 + xt) * 4 + c;
    _Float16* op = opart + ((size_t)slot * 64 + wave * 16 + col) * DD;
#pragma unroll
    for (int nn = 0; nn < 8; nn++) {
        f16x4 o4 = { (_Float16)Of[nn][0], (_Float16)Of[nn][1],
                     (_Float16)Of[nn][2], (_Float16)Of[nn][3] };
        *(f16x4*)&op[nn * 16 + quad * 4] = o4;
    }
    if (quad == 0) {
        mpart[slot * 64 + wave * 16 + col] = m_;
        lpart[slot * 64 + wave * 16 + col] = l_;
    }
}

// ---------------------------------------------------------------------------
// Kernel 3: combine up to 4 split-K partials per query row.
// ---------------------------------------------------------------------------
__global__ __launch_bounds__(256)
void combine_kernel(const _Float16* __restrict__ opart,
                    const float* __restrict__ mpart,
                    const float* __restrict__ lpart,
                    float* __restrict__ out)
{
    int gid = blockIdx.x * 256 + threadIdx.x;   // 0..2M-1
    int d   = gid & 127;
    int t   = gid >> 7;                         // global row 0..16383
    int b   = t >> 11;
    int tl  = t & (TT - 1);
    int xt  = tl >> 6;
    int rl  = tl & 63;
    int np  = (xt >> 3) + 1;                    // ceil((xt+1)/8)
    int sb  = (b * 32 + xt) * 4;

    float mm = -1e30f;
    for (int j = 0; j < np; j++)
        mm = fmaxf(mm, mpart[(sb + j) * 64 + rl]);
    float acc = 0.f, den = 0.f;
    for (int j = 0; j < np; j++) {
        float w = __builtin_amdgcn_exp2f(mpart[(sb + j) * 64 + rl] - mm);
        den += w * lpart[(sb + j) * 64 + rl];
        acc += w * (float)opart[((size_t)(sb + j) * 64 + rl) * DD + d];
    }
    out[gid] = acc / den;
}

extern "C" void kernel_launch(void* const* d_in, const int* in_sizes, int n_in,
                              void* d_out, int out_size, void* d_ws, size_t ws_size,
                              hipStream_t stream)
{
    const float* x  = (const float*)d_in[0];
    const float* Wq = (const float*)d_in[1];
    const float* Wk = (const float*)d_in[2];
    const float* Wv = (const float*)d_in[3];
    float* out = (float*)d_out;

    const size_t NTOK = (size_t)BB * TT;        // 16384
    _Float16* qh = (_Float16*)d_ws;             // 4 MB
    _Float16* kh = qh + NTOK * DD;              // 4 MB
    _Float16* vt = kh + NTOK * DD;              // 4 MB
    _Float16* Wt = vt + NTOK * DD;              // 0.75 MB
    _Float16* opart = Wt + (size_t)384 * EE;    // 16 MB (1024 slots x 64 x 128 f16)
    float* mp = (float*)(opart + (size_t)1024 * 64 * DD);   // 256 KB
    float* lp = mp + 1024 * 64;                 // 256 KB

    wt_prep_kernel<<<dim3(384), dim3(256), 0, stream>>>(Wq, Wk, Wv, Wt);
    proj_rope_kernel<<<dim3(512), dim3(512), 0, stream>>>(x, Wt, qh, kh, vt);
    attn_kernel<<<dim3(80, BB), dim3(256), 0, stream>>>(qh, kh, vt, opart, mp, lp);
    combine_kernel<<<dim3((int)(NTOK * DD / 256)), dim3(256), 0, stream>>>(opart, mp, lp, out);
}

// Round 5
// 184.529 us; speedup vs baseline: 3.5759x; 1.0628x over previous
//
#include <hip/hip_runtime.h>
#include <math.h>

#define BB 8
#define TT 2048
#define EE 1024
#define DD 128

typedef _Float16 f16x8 __attribute__((ext_vector_type(8)));
typedef _Float16 f16x4 __attribute__((ext_vector_type(4)));
typedef float    f32x4 __attribute__((ext_vector_type(4)));
typedef float    f32x16 __attribute__((ext_vector_type(16)));

// scale (128^-0.5) * log2(e): folded into q so softmax runs in exp2 domain
#define QSCALE 0.12752406f

// ---------------------------------------------------------------------------
// Kernel 0: W transpose+cast.  Wt[384][1024] f16 (rows 0-127=Wq^T, etc).
// ---------------------------------------------------------------------------
__global__ __launch_bounds__(256)
void wt_prep_kernel(const float* __restrict__ Wq,
                    const float* __restrict__ Wk,
                    const float* __restrict__ Wv,
                    _Float16* __restrict__ Wt)
{
    const int n = blockIdx.x;               // 0..383
    const int m = n >> 7;
    const float* __restrict__ W = (m == 0) ? Wq : (m == 1) ? Wk : Wv;
    const int nl = n & 127;
#pragma unroll
    for (int j = 0; j < 4; j++) {
        int kk = threadIdx.x + 256 * j;
        Wt[(size_t)n * EE + kk] = (_Float16)W[(size_t)kk * DD + nl];
    }
}

// ---------------------------------------------------------------------------
// Kernel 1: fused QKV projection, 32x32x16 MFMA, reg-prefetch double buffer.
// M-tile 64, N=384 (q|k|v), BK=64 -> 16 iters.  512 thr = 8 waves
// (wave_m{0,1} x wave_n{0..3}, 3 n-subtiles of 32 each).  grid = 256.
// 32x32 layouts (m74/m101): A[m=lane&31][k=half*8+j], B[k][n=lane&31],
// C row=(reg&3)+8*(reg>>2)+4*half, col=lane&31.
// ---------------------------------------------------------------------------
__global__ __launch_bounds__(512)
void proj_rope_kernel(const float* __restrict__ x,
                      const _Float16* __restrict__ Wt,
                      _Float16* __restrict__ qh,
                      _Float16* __restrict__ kh,
                      _Float16* __restrict__ vt)
{
    const int r0   = blockIdx.x * 64;       // 64 | 2048: never straddles batch
    const int tid  = threadIdx.x;
    const int wave = tid >> 6;
    const int lane = tid & 63;
    const int half = lane >> 5;
    const int col  = lane & 31;
    const int wave_m = wave & 1;
    const int wave_n = wave >> 1;

    __shared__ _Float16 Xs[64][72];         // stride 144B = 9x16B (odd) -> clean
    __shared__ _Float16 Ws[384][72];
    __shared__ _Float16 Out[64][136];

    f32x16 acc[3];
#pragma unroll
    for (int s = 0; s < 3; s++) acc[s] = (f32x16)0.f;

    const int xrow = tid >> 3, xc8 = (tid & 7) * 8;

    // prefetch iter 0
    float4 xa0, xa1;
    f16x8  wv[6];
    {
        const float* p = &x[(size_t)(r0 + xrow) * EE + xc8];
        xa0 = *(const float4*)p;
        xa1 = *(const float4*)(p + 4);
#pragma unroll
        for (int j = 0; j < 6; j++) {
            int ch = tid + 512 * j;
            int nn = ch >> 3, cw = (ch & 7) * 8;
            wv[j] = *(const f16x8*)&Wt[(size_t)nn * EE + cw];
        }
    }

    for (int it = 0; it < 16; it++) {
        __syncthreads();
        // LDS commit of prefetched tile
        {
            f16x8 h = { (_Float16)xa0.x, (_Float16)xa0.y, (_Float16)xa0.z, (_Float16)xa0.w,
                        (_Float16)xa1.x, (_Float16)xa1.y, (_Float16)xa1.z, (_Float16)xa1.w };
            *(f16x8*)&Xs[xrow][xc8] = h;
#pragma unroll
            for (int j = 0; j < 6; j++) {
                int ch = tid + 512 * j;
                int nn = ch >> 3, cw = (ch & 7) * 8;
                *(f16x8*)&Ws[nn][cw] = wv[j];
            }
        }
        // issue next-iter global loads (overlap with compute below)
        if (it + 1 < 16) {
            int k0 = (it + 1) * 64;
            const float* p = &x[(size_t)(r0 + xrow) * EE + k0 + xc8];
            xa0 = *(const float4*)p;
            xa1 = *(const float4*)(p + 4);
#pragma unroll
            for (int j = 0; j < 6; j++) {
                int ch = tid + 512 * j;
                int nn = ch >> 3, cw = (ch & 7) * 8;
                wv[j] = *(const f16x8*)&Wt[(size_t)nn * EE + k0 + cw];
            }
        }
        __syncthreads();
        // compute: 4 k-chunks x 3 n-subtiles
#pragma unroll
        for (int kc = 0; kc < 4; kc++) {
            f16x8 afr = *(f16x8*)&Xs[wave_m * 32 + col][kc * 16 + half * 8];
#pragma unroll
            for (int s = 0; s < 3; s++) {
                f16x8 bfr = *(f16x8*)&Ws[wave_n * 96 + s * 32 + col][kc * 16 + half * 8];
                acc[s] = __builtin_amdgcn_mfma_f32_32x32x16_f16(afr, bfr, acc[s], 0, 0, 0);
            }
        }
    }

    // ---- epilogue: RoPE + 3 coalesced store passes through Out ----
    const int bidx = r0 >> 11;
    const int t0   = r0 & (TT - 1);

    for (int p = 0; p < 3; p++) {
        __syncthreads();
#pragma unroll
        for (int s = 0; s < 3; s++) {
            int gs = wave_n * 3 + s;        // 0..11 global 32-col subtile
            if ((gs >> 2) != p) continue;
            int dcol = (gs & 3) * 32 + col; // 0..127 within matrix p
            float f = 0.f;
            if (p < 2)
                f = __powf(10000.0f, -(float)(dcol & ~1) * (1.0f / 128.0f));
#pragma unroll
            for (int rg = 0; rg < 16; rg++) {
                int mrow = wave_m * 32 + (rg & 3) + 8 * (rg >> 2) + 4 * half;
                float av = acc[s][rg];
                float res;
                if (p < 2) {
                    float ap = __shfl_xor(av, 1);   // RoPE pair partner (dcol^1)
                    float sa, ca;
                    __sincosf((float)(t0 + mrow) * f, &sa, &ca);
                    res = av * ca + ap * ((dcol & 1) ? sa : -sa);
                    if (p == 0) res *= QSCALE;
                } else {
                    res = av;
                }
                Out[mrow][dcol] = (_Float16)res;
            }
        }
        __syncthreads();
        if (p < 2) {
            _Float16* __restrict__ dst = ((p == 0) ? qh : kh) + (size_t)r0 * DD;
#pragma unroll
            for (int j = 0; j < 2; j++) {
                int cidx = tid + 512 * j;   // 1024 chunks = 64 rows x 16
                int row = cidx >> 4, o = cidx & 15;
                *(f16x8*)&dst[(size_t)row * DD + o * 8] = *(f16x8*)&Out[row][o * 8];
            }
        } else {
#pragma unroll
            for (int j = 0; j < 2; j++) {
                int u = tid + 512 * j;      // 1024 = 128 d x 8 t-chunks
                int d = u >> 3, tg = u & 7;
                f16x8 vv;
#pragma unroll
                for (int e = 0; e < 8; e++) vv[e] = Out[tg * 8 + e][d];
                *(f16x8*)&vt[((size_t)(bidx * DD + d)) * TT + t0 + tg * 8] = vv;
            }
        }
    }
}

// ---------------------------------------------------------------------------
// Kernel 2: MFMA flash attention, transposed softmax, 32x32x16 MFMA,
// Q-tile 128 (4 waves x 32 q), K-tile 64, reg-prefetch double buffer.
// Chunked split-K: <=8 k-tiles per block; grid.x = 40 (big chunks first).
// ---------------------------------------------------------------------------
__global__ __launch_bounds__(256)
void attn_kernel(const _Float16* __restrict__ qh,
                 const _Float16* __restrict__ kh,
                 const _Float16* __restrict__ vth,
                 _Float16* __restrict__ opart,
                 float* __restrict__ mpart,
                 float* __restrict__ lpart)
{
    const int b  = blockIdx.y;
    const int v_ = 39 - blockIdx.x;         // ascending-work table, reversed
    int xt, c;
    if (v_ < 4)       { xt = v_;                  c = 0; }
    else if (v_ < 12) { xt = 4 + ((v_ - 4) >> 1); c = (v_ - 4) & 1; }
    else if (v_ < 24) { xt = 8 + (v_ - 12) / 3;   c = (v_ - 12) % 3; }
    else              { xt = 12 + ((v_ - 24) >> 2); c = (v_ - 24) & 3; }
    const int q0 = xt * 128;
    const int nt = 2 * xt + 2;              // causal 64-key tiles
    const int kt_begin = c * 8;
    const int kt_end   = (kt_begin + 8 < nt) ? (kt_begin + 8) : nt;

    const int tid  = threadIdx.x;
    const int wave = tid >> 6;
    const int lane = tid & 63;
    const int half = lane >> 5;
    const int col  = lane & 31;

    __shared__ _Float16 Ks[64][136];        // [key][dim]
    __shared__ _Float16 Vt[128][72];        // [dim][key]
    __shared__ _Float16 Ps[4][32][72];      // [wave][q][key]

    const int qg = q0 + wave * 32 + col;    // this lane's query
    f16x8 qb[8];                            // Q as B-frag (dims = k)
#pragma unroll
    for (int kc = 0; kc < 8; kc++)
        qb[kc] = *(const f16x8*)&qh[((size_t)b * TT + qg) * DD + kc * 16 + half * 8];

    f32x16 Of[4];                           // O^T: 4 d-subtiles x 32 q
#pragma unroll
    for (int t = 0; t < 4; t++) Of[t] = (f32x16)0.f;
    float m_ = -1e30f, l_ = 0.f;

    // prefetch first tile
    f16x8 kr[4], vr[4];
    {
        const int kb0 = kt_begin * 64;
#pragma unroll
        for (int i = 0; i < 4; i++) {
            int idx = i * 256 + tid;
            int key = idx >> 4, cc = idx & 15;
            kr[i] = *(const f16x8*)&kh[((size_t)b * TT + kb0 + key) * DD + cc * 8];
        }
#pragma unroll
        for (int i = 0; i < 4; i++) {
            int idx = i * 256 + tid;
            int d = idx >> 3, cc = idx & 7;
            vr[i] = *(const f16x8*)&vth[((size_t)b * DD + d) * TT + kb0 + cc * 8];
        }
    }

    for (int kt = kt_begin; kt < kt_end; kt++) {
        const int kb0 = kt * 64;
        __syncthreads();
        // commit prefetched tile to LDS
#pragma unroll
        for (int i = 0; i < 4; i++) {
            int idx = i * 256 + tid;
            int key = idx >> 4, cc = idx & 15;
            *(f16x8*)&Ks[key][cc * 8] = kr[i];
        }
#pragma unroll
        for (int i = 0; i < 4; i++) {
            int idx = i * 256 + tid;
            int d = idx >> 3, cc = idx & 7;
            *(f16x8*)&Vt[d][cc * 8] = vr[i];
        }
        // issue next-tile loads (overlap with compute)
        if (kt + 1 < kt_end) {
            const int kb1 = kb0 + 64;
#pragma unroll
            for (int i = 0; i < 4; i++) {
                int idx = i * 256 + tid;
                int key = idx >> 4, cc = idx & 15;
                kr[i] = *(const f16x8*)&kh[((size_t)b * TT + kb1 + key) * DD + cc * 8];
            }
#pragma unroll
            for (int i = 0; i < 4; i++) {
                int idx = i * 256 + tid;
                int d = idx >> 3, cc = idx & 7;
                vr[i] = *(const f16x8*)&vth[((size_t)b * DD + d) * TT + kb1 + cc * 8];
            }
        }
        __syncthreads();

        // ---- S^T = K Q^T : rows = keys, cols = queries ----
        f32x16 sf[2];
#pragma unroll
        for (int g = 0; g < 2; g++) {
            sf[g] = (f32x16)0.f;
#pragma unroll
            for (int kc = 0; kc < 8; kc++) {
                f16x8 kf = *(f16x8*)&Ks[g * 32 + col][kc * 16 + half * 8];
                sf[g] = __builtin_amdgcn_mfma_f32_32x32x16_f16(kf, qb[kc], sf[g], 0, 0, 0);
            }
        }

        // ---- softmax: 32 key-scores in-lane, ONE shfl step (xor 32) ----
        const bool diag = (kt >= 2 * xt);
        float mloc = -1e30f;
#pragma unroll
        for (int g = 0; g < 2; g++)
#pragma unroll
            for (int rg = 0; rg < 16; rg++) {
                int key = kb0 + g * 32 + (rg & 3) + 8 * (rg >> 2) + 4 * half;
                float val = sf[g][rg];
                val = (!diag || key <= qg) ? val : -1e30f;
                sf[g][rg] = val;
                mloc = fmaxf(mloc, val);
            }
        mloc = fmaxf(mloc, __shfl_xor(mloc, 32));
        float mnew  = fmaxf(m_, mloc);
        float alpha = __builtin_amdgcn_exp2f(m_ - mnew);
        float ps = 0.f;
#pragma unroll
        for (int g = 0; g < 2; g++) {
#pragma unroll
            for (int rc = 0; rc < 4; rc++) {
                f16x4 p4;
#pragma unroll
                for (int rr = 0; rr < 4; rr++) {
                    float p = __builtin_amdgcn_exp2f(sf[g][4 * rc + rr] - mnew);
                    ps += p;
                    p4[rr] = (_Float16)p;
                }
                *(f16x4*)&Ps[wave][col][g * 32 + 8 * rc + 4 * half] = p4;
            }
        }
        ps += __shfl_xor(ps, 32);
        l_ = l_ * alpha + ps;
        m_ = mnew;
#pragma unroll
        for (int t = 0; t < 4; t++) Of[t] *= alpha;

        // ---- O^T += V^T P^T (P via same-wave LDS round-trip) ----
        f16x8 pb[4];
#pragma unroll
        for (int kc = 0; kc < 4; kc++)
            pb[kc] = *(f16x8*)&Ps[wave][col][kc * 16 + half * 8];
#pragma unroll
        for (int t = 0; t < 4; t++) {
#pragma unroll
            for (int kc = 0; kc < 4; kc++) {
                f16x8 vf = *(f16x8*)&Vt[t * 32 + col][kc * 16 + half * 8];
                Of[t] = __builtin_amdgcn_mfma_f32_32x32x16_f16(vf, pb[kc], Of[t], 0, 0, 0);
            }
        }
    }

    // ---- partial store (f16 unnormalized O^T -> [q][d], f32 m/l) ----
    const int slot = (b * 16 + xt) * 4 + c;
    _Float16* op = opart + ((size_t)slot * 128 + wave * 32 + col) * DD;
#pragma unroll
    for (int t = 0; t < 4; t++) {
#pragma unroll
        for (int rc = 0; rc < 4; rc++) {
            f16x4 o4 = { (_Float16)Of[t][4 * rc + 0], (_Float16)Of[t][4 * rc + 1],
                         (_Float16)Of[t][4 * rc + 2], (_Float16)Of[t][4 * rc + 3] };
            *(f16x4*)&op[t * 32 + 8 * rc + 4 * half] = o4;
        }
    }
    if (half == 0) {
        mpart[slot * 128 + wave * 32 + col] = m_;
        lpart[slot * 128 + wave * 32 + col] = l_;
    }
}

// ---------------------------------------------------------------------------
// Kernel 3: combine up to 4 split-K partials per query row.
// ---------------------------------------------------------------------------
__global__ __launch_bounds__(256)
void combine_kernel(const _Float16* __restrict__ opart,
                    const float* __restrict__ mpart,
                    const float* __restrict__ lpart,
                    float* __restrict__ out)
{
    int gid = blockIdx.x * 256 + threadIdx.x;   // 0..2M-1
    int d   = gid & 127;
    int t   = gid >> 7;                         // 0..16383
    int b   = t >> 11;
    int tl  = t & (TT - 1);
    int xt  = tl >> 7;
    int rl  = tl & 127;
    int np  = (2 * xt + 2 + 7) >> 3;
    int sb  = (b * 16 + xt) * 4;

    float mm = -1e30f;
    for (int j = 0; j < np; j++)
        mm = fmaxf(mm, mpart[(sb + j) * 128 + rl]);
    float acc = 0.f, den = 0.f;
    for (int j = 0; j < np; j++) {
        float w = __builtin_amdgcn_exp2f(mpart[(sb + j) * 128 + rl] - mm);
        den += w * lpart[(sb + j) * 128 + rl];
        acc += w * (float)opart[((size_t)(sb + j) * 128 + rl) * DD + d];
    }
    out[gid] = acc / den;
}

extern "C" void kernel_launch(void* const* d_in, const int* in_sizes, int n_in,
                              void* d_out, int out_size, void* d_ws, size_t ws_size,
                              hipStream_t stream)
{
    const float* x  = (const float*)d_in[0];
    const float* Wq = (const float*)d_in[1];
    const float* Wk = (const float*)d_in[2];
    const float* Wv = (const float*)d_in[3];
    float* out = (float*)d_out;

    const size_t NTOK = (size_t)BB * TT;        // 16384
    _Float16* qh = (_Float16*)d_ws;             // 4 MB
    _Float16* kh = qh + NTOK * DD;              // 4 MB
    _Float16* vt = kh + NTOK * DD;              // 4 MB
    _Float16* Wt = vt + NTOK * DD;              // 0.75 MB
    _Float16* opart = Wt + (size_t)384 * EE;    // 16 MB (512 slots x 128 x 128)
    float* mp = (float*)(opart + (size_t)512 * 128 * DD);   // 256 KB
    float* lp = mp + 512 * 128;                 // 256 KB

    wt_prep_kernel<<<dim3(384), dim3(256), 0, stream>>>(Wq, Wk, Wv, Wt);
    proj_rope_kernel<<<dim3(256), dim3(512), 0, stream>>>(x, Wt, qh, kh, vt);
    attn_kernel<<<dim3(40, BB), dim3(256), 0, stream>>>(qh, kh, vt, opart, mp, lp);
    combine_kernel<<<dim3((int)(NTOK * DD / 256)), dim3(256), 0, stream>>>(opart, mp, lp, out);
}